// Round 1
// baseline (251.834 us; speedup 1.0000x reference)
//
#include <hip/hip_runtime.h>
#include <math.h>

#define NB 4
#define NS 2048
#define DMODEL 1024
#define DSPACE 64
#define NPOOL 512
#define NHEADS 6
#define NTOK (NB * NS)            // 8192
#define PROJN (NHEADS * DSPACE)   // 384
#define EPSF 1e-8f

// ---------------- K1: normalize neuron_emb rows [0,2048) -> embT[64][2048]
__global__ __launch_bounds__(256) void k_norm_emb(const float* __restrict__ emb,
                                                  float* __restrict__ embT) {
    int row  = blockIdx.x * 4 + (threadIdx.x >> 6);
    int lane = threadIdx.x & 63;
    float v  = emb[row * DSPACE + lane];
    float ss = v * v;
#pragma unroll
    for (int off = 32; off >= 1; off >>= 1) ss += __shfl_xor(ss, off, 64);
    float nrm = sqrtf(ss) + EPSF;
    embT[lane * 2048 + row] = v / nrm;
}

// ---------------- K2: proj[8192,384] = X[8192,1024] @ W[1024,384] + b
#define BM 64
#define BN 64
#define BK 32

__global__ __launch_bounds__(256) void k_proj(const float* __restrict__ X,
                                              const float* __restrict__ W,
                                              const float* __restrict__ bias,
                                              float* __restrict__ P) {
    __shared__ float Xt[BK][BM + 4];   // transposed X tile, stride 68 (16B aligned rows)
    __shared__ float Wt[BK][BN];
    const int tid = threadIdx.x;
    const int bm  = blockIdx.x * BM;
    const int bn  = blockIdx.y * BN;
    const int tm  = (tid >> 4) << 2;   // 0..60
    const int tn  = (tid & 15) << 2;   // 0..60
    const int lxm = tid >> 3;          // 0..31
    const int lxk = (tid & 7) << 2;    // 0..28
    const int lwk = tid >> 4;          // 0..15
    const int lwn = (tid & 15) << 2;   // 0..60

    float acc[4][4] = {{0.f}};
    for (int k0 = 0; k0 < DMODEL; k0 += BK) {
        float4 xa = *(const float4*)&X[(size_t)(bm + lxm) * DMODEL + k0 + lxk];
        float4 xb = *(const float4*)&X[(size_t)(bm + lxm + 32) * DMODEL + k0 + lxk];
        float4 wa = *(const float4*)&W[(size_t)(k0 + lwk) * PROJN + bn + lwn];
        float4 wb = *(const float4*)&W[(size_t)(k0 + lwk + 16) * PROJN + bn + lwn];
        __syncthreads();
        Xt[lxk + 0][lxm] = xa.x; Xt[lxk + 1][lxm] = xa.y;
        Xt[lxk + 2][lxm] = xa.z; Xt[lxk + 3][lxm] = xa.w;
        Xt[lxk + 0][lxm + 32] = xb.x; Xt[lxk + 1][lxm + 32] = xb.y;
        Xt[lxk + 2][lxm + 32] = xb.z; Xt[lxk + 3][lxm + 32] = xb.w;
        *(float4*)&Wt[lwk][lwn] = wa;
        *(float4*)&Wt[lwk + 16][lwn] = wb;
        __syncthreads();
#pragma unroll
        for (int kk = 0; kk < BK; ++kk) {
            float4 a4 = *(const float4*)&Xt[kk][tm];
            float4 b4 = *(const float4*)&Wt[kk][tn];
            float av[4] = {a4.x, a4.y, a4.z, a4.w};
            float bv[4] = {b4.x, b4.y, b4.z, b4.w};
#pragma unroll
            for (int i = 0; i < 4; ++i)
#pragma unroll
                for (int j = 0; j < 4; ++j)
                    acc[i][j] = fmaf(av[i], bv[j], acc[i][j]);
        }
    }
#pragma unroll
    for (int i = 0; i < 4; ++i) {
        float o[4];
#pragma unroll
        for (int j = 0; j < 4; ++j) o[j] = acc[i][j] + bias[bn + tn + j];
        *(float4*)&P[(size_t)(bm + tm + i) * PROJN + bn + tn] = *(float4*)&o[0];
    }
}

// ---------------- K3: per (head, 32-token block): logits + softmax + top8 + dense write
__global__ __launch_bounds__(256) void k_router(const float* __restrict__ P,
                                                const float* __restrict__ embT,
                                                float* __restrict__ out) {
    __shared__ float hsh[32][DSPACE];   // 8 KB
    const int head = blockIdx.y;
    const int t0   = blockIdx.x * 32;
    const int tid  = threadIdx.x;
    const int wid  = tid >> 6;
    const int lane = tid & 63;
    // segment offsets: {0,0,512,1024,1024,1536}
    const int so = (head == 2) ? 512 : (head == 3 || head == 4) ? 1024
                 : (head == 5) ? 1536 : 0;

    // stage h tile: 32 tokens x 64 dims
    for (int idx = tid; idx < 512; idx += 256) {
        int t = idx >> 4;
        int d4 = (idx & 15) << 2;
        float4 v = *(const float4*)&P[(size_t)(t0 + t) * PROJN + head * DSPACE + d4];
        *(float4*)&hsh[t][d4] = v;
    }
    __syncthreads();

    // logits: wave handles 8 tokens; lane owns n = 8*lane + j
    float acc[8][8];
#pragma unroll
    for (int t = 0; t < 8; ++t)
#pragma unroll
        for (int j = 0; j < 8; ++j) acc[t][j] = 0.f;

#pragma unroll 2
    for (int d = 0; d < DSPACE; ++d) {
        const float* er = &embT[d * 2048 + so + (lane << 3)];
        float e[8];
        *(float4*)&e[0] = *(const float4*)&er[0];
        *(float4*)&e[4] = *(const float4*)&er[4];
#pragma unroll
        for (int t = 0; t < 8; ++t) {
            float hv = hsh[(wid << 3) + t][d];   // broadcast
#pragma unroll
            for (int j = 0; j < 8; ++j) acc[t][j] = fmaf(hv, e[j], acc[t][j]);
        }
    }

    const size_t obase = ((size_t)head * NTOK + t0 + (wid << 3)) * NPOOL;
#pragma unroll 1
    for (int t = 0; t < 8; ++t) {
        float l[8];
#pragma unroll
        for (int j = 0; j < 8; ++j) l[j] = acc[t][j];
        // row max
        float m = l[0];
#pragma unroll
        for (int j = 1; j < 8; ++j) m = fmaxf(m, l[j]);
#pragma unroll
        for (int off = 32; off >= 1; off >>= 1) m = fmaxf(m, __shfl_xor(m, off, 64));
        // softmax denominator Z
        float z = 0.f;
#pragma unroll
        for (int j = 0; j < 8; ++j) z += __expf(l[j] - m);
#pragma unroll
        for (int off = 32; off >= 1; off >>= 1) z += __shfl_xor(z, off, 64);
        // iterative top-8 (tie-break: lowest index, matching jax.lax.top_k)
        float w[8];
#pragma unroll
        for (int j = 0; j < 8; ++j) w[j] = l[j];
        float s8 = 0.f;
        unsigned sel = 0;
        for (int r = 0; r < 8; ++r) {
            float lv = w[0]; int lj = 0;
#pragma unroll
            for (int j = 1; j < 8; ++j)
                if (w[j] > lv) { lv = w[j]; lj = j; }
            float bv = lv;
            int   bi = (lane << 3) | lj;
#pragma unroll
            for (int off = 1; off < 64; off <<= 1) {
                float ov = __shfl_xor(bv, off, 64);
                int   oi = __shfl_xor(bi, off, 64);
                if (ov > bv || (ov == bv && oi < bi)) { bv = ov; bi = oi; }
            }
            s8 += __expf(bv - m);
            if ((bi >> 3) == lane) {
                int jj = bi & 7;
#pragma unroll
                for (int j = 0; j < 8; ++j)
                    if (j == jj) { w[j] = -INFINITY; sel |= (1u << j); }
            }
        }
        // out = exp(l-m) / (s8 + EPS*Z) at selected, else 0
        float inv = 1.0f / (s8 + EPSF * z);
        float o[8];
#pragma unroll
        for (int j = 0; j < 8; ++j)
            o[j] = ((sel >> j) & 1u) ? __expf(l[j] - m) * inv : 0.0f;
        float4* dst = (float4*)&out[obase + (size_t)t * NPOOL + (lane << 3)];
        dst[0] = *(float4*)&o[0];
        dst[1] = *(float4*)&o[4];
    }
}

extern "C" void kernel_launch(void* const* d_in, const int* in_sizes, int n_in,
                              void* d_out, int out_size, void* d_ws, size_t ws_size,
                              hipStream_t stream) {
    const float* x   = (const float*)d_in[0];
    const float* W   = (const float*)d_in[1];
    const float* b   = (const float*)d_in[2];
    const float* emb = (const float*)d_in[3];
    float* out  = (float*)d_out;
    float* embT = (float*)d_ws;               // 64*2048 floats = 512 KB
    float* proj = embT + 64 * 2048;           // 8192*384 floats = 12.6 MB

    k_norm_emb<<<dim3(512), dim3(256), 0, stream>>>(emb, embT);
    dim3 g2(NTOK / BM, PROJN / BN);
    k_proj<<<g2, dim3(256), 0, stream>>>(x, W, b, proj);
    dim3 g3(NTOK / 32, NHEADS);
    k_router<<<g3, dim3(256), 0, stream>>>(proj, embT, out);
}

// Round 2
// 186.268 us; speedup vs baseline: 1.3520x; 1.3520x over previous
//
#include <hip/hip_runtime.h>
#include <math.h>

#define NB 4
#define NS 2048
#define DMODEL 1024
#define DSPACE 64
#define NPOOL 512
#define NHEADS 6
#define NTOK (NB * NS)            // 8192
#define PROJN (NHEADS * DSPACE)   // 384
#define EPSF 1e-8f

// ---------------- K1: normalize neuron_emb rows [0,2048) -> embT[64][2048]
__global__ __launch_bounds__(256) void k_norm_emb(const float* __restrict__ emb,
                                                  float* __restrict__ embT) {
    int row  = blockIdx.x * 4 + (threadIdx.x >> 6);
    int lane = threadIdx.x & 63;
    float v  = emb[row * DSPACE + lane];
    float ss = v * v;
#pragma unroll
    for (int off = 32; off >= 1; off >>= 1) ss += __shfl_xor(ss, off, 64);
    float nrm = sqrtf(ss) + EPSF;
    embT[lane * 2048 + row] = v / nrm;
}

// ---------------- K2: proj[8192,384] = X[8192,1024] @ W[1024,384] + b
#define BM 64
#define BN 64
#define BK 32

__global__ __launch_bounds__(256) void k_proj(const float* __restrict__ X,
                                              const float* __restrict__ W,
                                              const float* __restrict__ bias,
                                              float* __restrict__ P) {
    __shared__ float Xt[BK][BM + 4];
    __shared__ float Wt[BK][BN];
    const int tid = threadIdx.x;
    const int bm  = blockIdx.x * BM;
    const int bn  = blockIdx.y * BN;
    const int tm  = (tid >> 4) << 2;
    const int tn  = (tid & 15) << 2;
    const int lxm = tid >> 3;
    const int lxk = (tid & 7) << 2;
    const int lwk = tid >> 4;
    const int lwn = (tid & 15) << 2;

    float acc[4][4] = {{0.f}};
    for (int k0 = 0; k0 < DMODEL; k0 += BK) {
        float4 xa = *(const float4*)&X[(size_t)(bm + lxm) * DMODEL + k0 + lxk];
        float4 xb = *(const float4*)&X[(size_t)(bm + lxm + 32) * DMODEL + k0 + lxk];
        float4 wa = *(const float4*)&W[(size_t)(k0 + lwk) * PROJN + bn + lwn];
        float4 wb = *(const float4*)&W[(size_t)(k0 + lwk + 16) * PROJN + bn + lwn];
        __syncthreads();
        Xt[lxk + 0][lxm] = xa.x; Xt[lxk + 1][lxm] = xa.y;
        Xt[lxk + 2][lxm] = xa.z; Xt[lxk + 3][lxm] = xa.w;
        Xt[lxk + 0][lxm + 32] = xb.x; Xt[lxk + 1][lxm + 32] = xb.y;
        Xt[lxk + 2][lxm + 32] = xb.z; Xt[lxk + 3][lxm + 32] = xb.w;
        *(float4*)&Wt[lwk][lwn] = wa;
        *(float4*)&Wt[lwk + 16][lwn] = wb;
        __syncthreads();
#pragma unroll
        for (int kk = 0; kk < BK; ++kk) {
            float4 a4 = *(const float4*)&Xt[kk][tm];
            float4 b4 = *(const float4*)&Wt[kk][tn];
            float av[4] = {a4.x, a4.y, a4.z, a4.w};
            float bv[4] = {b4.x, b4.y, b4.z, b4.w};
#pragma unroll
            for (int i = 0; i < 4; ++i)
#pragma unroll
                for (int j = 0; j < 4; ++j)
                    acc[i][j] = fmaf(av[i], bv[j], acc[i][j]);
        }
    }
#pragma unroll
    for (int i = 0; i < 4; ++i) {
        float o[4];
#pragma unroll
        for (int j = 0; j < 4; ++j) o[j] = acc[i][j] + bias[bn + tn + j];
        *(float4*)&P[(size_t)(bm + tm + i) * PROJN + bn + tn] = *(float4*)&o[0];
    }
}

// compare-exchange keeping larger value at index a (descending order)
#define CE(arr, a, b) { float _hi = fmaxf(arr[a], arr[b]); arr[b] = fminf(arr[a], arr[b]); arr[a] = _hi; }

// ---------------- K3: logits + softmax + top8 (merge-butterfly) + dense write
__global__ __launch_bounds__(256) void k_router(const float* __restrict__ P,
                                                const float* __restrict__ embT,
                                                float* __restrict__ out) {
    __shared__ float hsh[32][DSPACE];   // 8 KB
    const int head = blockIdx.y;
    const int t0   = blockIdx.x * 32;
    const int tid  = threadIdx.x;
    const int wid  = tid >> 6;
    const int lane = tid & 63;
    const int so = (head == 2) ? 512 : (head == 3 || head == 4) ? 1024
                 : (head == 5) ? 1536 : 0;

    // stage h tile: 32 tokens x 64 dims
    for (int idx = tid; idx < 512; idx += 256) {
        int t  = idx >> 4;
        int d4 = (idx & 15) << 2;
        *(float4*)&hsh[t][d4] =
            *(const float4*)&P[(size_t)(t0 + t) * PROJN + head * DSPACE + d4];
    }
    __syncthreads();

    // logits: wave handles 8 tokens; lane owns n = 8*lane + j
    float acc[8][8];
#pragma unroll
    for (int t = 0; t < 8; ++t)
#pragma unroll
        for (int j = 0; j < 8; ++j) acc[t][j] = 0.f;

#pragma unroll 2
    for (int d = 0; d < DSPACE; ++d) {
        const float* er = &embT[d * 2048 + so + (lane << 3)];
        float e[8];
        *(float4*)&e[0] = *(const float4*)&er[0];
        *(float4*)&e[4] = *(const float4*)&er[4];
#pragma unroll
        for (int t = 0; t < 8; ++t) {
            float hv = hsh[(wid << 3) + t][d];   // LDS broadcast
#pragma unroll
            for (int j = 0; j < 8; ++j) acc[t][j] = fmaf(hv, e[j], acc[t][j]);
        }
    }

    const size_t obase = ((size_t)head * NTOK + t0 + (wid << 3)) * NPOOL;

#pragma unroll
    for (int t = 0; t < 8; ++t) {
        float l[8], s[8];
#pragma unroll
        for (int j = 0; j < 8; ++j) { l[j] = acc[t][j]; s[j] = l[j]; }

        // ---- per-lane descending sort of 8 values (Batcher odd-even, 19 CE)
        CE(s,0,1) CE(s,2,3) CE(s,4,5) CE(s,6,7)
        CE(s,0,2) CE(s,1,3) CE(s,4,6) CE(s,5,7)
        CE(s,1,2) CE(s,5,6)
        CE(s,0,4) CE(s,1,5) CE(s,2,6) CE(s,3,7)
        CE(s,2,4) CE(s,3,5)
        CE(s,1,2) CE(s,3,4) CE(s,5,6)

        // ---- butterfly merge: after 6 steps every lane holds global top-8 desc
#pragma unroll
        for (int off = 1; off < 64; off <<= 1) {
            float q[8];
#pragma unroll
            for (int i = 0; i < 8; ++i) q[i] = __shfl_xor(s[i], off, 64);
            float c[8];
            c[0] = fmaxf(s[0], q[7]); c[1] = fmaxf(s[1], q[6]);
            c[2] = fmaxf(s[2], q[5]); c[3] = fmaxf(s[3], q[4]);
            c[4] = fmaxf(s[4], q[3]); c[5] = fmaxf(s[5], q[2]);
            c[6] = fmaxf(s[6], q[1]); c[7] = fmaxf(s[7], q[0]);
            // bitonic descending cleanup (12 CE)
            CE(c,0,4) CE(c,1,5) CE(c,2,6) CE(c,3,7)
            CE(c,0,2) CE(c,1,3) CE(c,4,6) CE(c,5,7)
            CE(c,0,1) CE(c,2,3) CE(c,4,5) CE(c,6,7)
#pragma unroll
            for (int i = 0; i < 8; ++i) s[i] = c[i];
        }

        const float T = s[7];    // 8th largest (selection threshold)
        const float m = s[0];    // row max

        // exp once per element; partial softmax denominator
        float e[8]; float zp = 0.f;
#pragma unroll
        for (int j = 0; j < 8; ++j) { e[j] = __expf(l[j] - m); zp += e[j]; }
#pragma unroll
        for (int off = 32; off >= 1; off >>= 1) zp += __shfl_xor(zp, off, 64);

        // selection: all l>T, plus (8 - #gt) of l==T by ascending global index
        unsigned gtm = 0, eqm = 0; int cgt = 0, ceq = 0;
#pragma unroll
        for (int j = 0; j < 8; ++j) {
            if (l[j] > T)       { gtm |= 1u << j; ++cgt; }
            else if (l[j] == T) { eqm |= 1u << j; ++ceq; }
        }
        int own = (ceq << 8) | cgt;
        int inc = own;
#pragma unroll
        for (int off = 1; off < 64; off <<= 1) {
            int v = __shfl_up(inc, off, 64);
            if (lane >= off) inc += v;
        }
        int tot  = __shfl(inc, 63, 64);
        int need = 8 - (tot & 0xff);
        int eqpre = (inc - own) >> 8;      // exclusive prefix of eq count
        unsigned sel = gtm;
#pragma unroll
        for (int j = 0; j < 8; ++j) {
            if ((eqm >> j) & 1u) { if (eqpre < need) sel |= 1u << j; ++eqpre; }
        }

        // s8 = sum of exps over the selected set == over the top-8 value list
        float s8 = 0.f;
#pragma unroll
        for (int i = 0; i < 8; ++i) s8 += __expf(s[i] - m);
        float invd = 1.0f / (s8 + EPSF * zp);

        float o[8];
#pragma unroll
        for (int j = 0; j < 8; ++j)
            o[j] = ((sel >> j) & 1u) ? e[j] * invd : 0.0f;
        float4* dst = (float4*)&out[obase + (size_t)t * NPOOL + (lane << 3)];
        dst[0] = *(float4*)&o[0];
        dst[1] = *(float4*)&o[4];
    }
}

extern "C" void kernel_launch(void* const* d_in, const int* in_sizes, int n_in,
                              void* d_out, int out_size, void* d_ws, size_t ws_size,
                              hipStream_t stream) {
    const float* x   = (const float*)d_in[0];
    const float* W   = (const float*)d_in[1];
    const float* b   = (const float*)d_in[2];
    const float* emb = (const float*)d_in[3];
    float* out  = (float*)d_out;
    float* embT = (float*)d_ws;               // 64*2048 floats = 512 KB
    float* proj = embT + 64 * 2048;           // 8192*384 floats = 12.6 MB

    k_norm_emb<<<dim3(512), dim3(256), 0, stream>>>(emb, embT);
    dim3 g2(NTOK / BM, PROJN / BN);
    k_proj<<<g2, dim3(256), 0, stream>>>(x, W, b, proj);
    dim3 g3(NTOK / 32, NHEADS);
    k_router<<<g3, dim3(256), 0, stream>>>(proj, embT, out);
}

// Round 3
// 184.061 us; speedup vs baseline: 1.3682x; 1.0120x over previous
//
#include <hip/hip_runtime.h>
#include <math.h>

#define NB 4
#define NS 2048
#define DMODEL 1024
#define DSPACE 64
#define NPOOL 512
#define NHEADS 6
#define NTOK (NB * NS)            // 8192
#define PROJN (NHEADS * DSPACE)   // 384
#define EPSF 1e-8f

// ---------------- K1: normalize neuron_emb rows [0,2048) -> embT[64][2048]
__global__ __launch_bounds__(256) void k_norm_emb(const float* __restrict__ emb,
                                                  float* __restrict__ embT) {
    int row  = blockIdx.x * 4 + (threadIdx.x >> 6);
    int lane = threadIdx.x & 63;
    float v  = emb[row * DSPACE + lane];
    float ss = v * v;
#pragma unroll
    for (int off = 32; off >= 1; off >>= 1) ss += __shfl_xor(ss, off, 64);
    float nrm = sqrtf(ss) + EPSF;
    embT[lane * 2048 + row] = v / nrm;
}

// ---------------- K2: proj[8192,384] = X[8192,1024] @ W[1024,384] + b
#define BM 64
#define BN 64
#define BK 32

// Xt swizzle: element (kk, m) lives at  kk*64 + (((m>>2)^(kk>>2))<<2) + (m&3)
__global__ __launch_bounds__(256) void k_proj(const float* __restrict__ X,
                                              const float* __restrict__ W,
                                              const float* __restrict__ bias,
                                              float* __restrict__ P) {
    __shared__ float Xt[BK * BM];      // 8 KB, swizzled
    __shared__ float Wt[BK][BN];       // 8 KB
    const int tid = threadIdx.x;
    const int bm  = blockIdx.x * BM;
    const int bn  = blockIdx.y * BN;
    const int tm  = (tid >> 4) << 2;   // 0..60
    const int tn  = (tid & 15) << 2;   // 0..60
    const int lxm = tid >> 3;          // 0..31
    const int lxk = (tid & 7) << 2;    // 0..28 (multiple of 4)
    const int lwk = tid >> 4;          // 0..15
    const int lwn = (tid & 15) << 2;   // 0..60

    // swizzled store bases (kk>>2 == lxk>>2 constant over the 4 stored kk)
    const int pgA = ((((lxm)      >> 2) ^ (lxk >> 2)) << 2) + (lxm & 3);
    const int pgB = ((((lxm + 32) >> 2) ^ (lxk >> 2)) << 2) + (lxm & 3);

    float acc[4][4] = {{0.f}};
    for (int k0 = 0; k0 < DMODEL; k0 += BK) {
        float4 xa = *(const float4*)&X[(size_t)(bm + lxm) * DMODEL + k0 + lxk];
        float4 xb = *(const float4*)&X[(size_t)(bm + lxm + 32) * DMODEL + k0 + lxk];
        float4 wa = *(const float4*)&W[(size_t)(k0 + lwk) * PROJN + bn + lwn];
        float4 wb = *(const float4*)&W[(size_t)(k0 + lwk + 16) * PROJN + bn + lwn];
        __syncthreads();
        Xt[(lxk + 0) * BM + pgA] = xa.x; Xt[(lxk + 1) * BM + pgA] = xa.y;
        Xt[(lxk + 2) * BM + pgA] = xa.z; Xt[(lxk + 3) * BM + pgA] = xa.w;
        Xt[(lxk + 0) * BM + pgB] = xb.x; Xt[(lxk + 1) * BM + pgB] = xb.y;
        Xt[(lxk + 2) * BM + pgB] = xb.z; Xt[(lxk + 3) * BM + pgB] = xb.w;
        *(float4*)&Wt[lwk][lwn] = wa;
        *(float4*)&Wt[lwk + 16][lwn] = wb;
        __syncthreads();
#pragma unroll
        for (int kk = 0; kk < BK; ++kk) {
            float4 a4 = *(const float4*)&Xt[kk * BM + ((((tm >> 2) ^ (kk >> 2)) << 2))];
            float4 b4 = *(const float4*)&Wt[kk][tn];
            float av[4] = {a4.x, a4.y, a4.z, a4.w};
            float bv[4] = {b4.x, b4.y, b4.z, b4.w};
#pragma unroll
            for (int i = 0; i < 4; ++i)
#pragma unroll
                for (int j = 0; j < 4; ++j)
                    acc[i][j] = fmaf(av[i], bv[j], acc[i][j]);
        }
    }
#pragma unroll
    for (int i = 0; i < 4; ++i) {
        float o[4];
#pragma unroll
        for (int j = 0; j < 4; ++j) o[j] = acc[i][j] + bias[bn + tn + j];
        *(float4*)&P[(size_t)(bm + tm + i) * PROJN + bn + tn] = *(float4*)&o[0];
    }
}

// compare-exchange keeping larger value at index a (descending order)
#define CE(arr, a, b) { float _hi = fmaxf(arr[a], arr[b]); arr[b] = fminf(arr[a], arr[b]); arr[a] = _hi; }

// ---------------- K3: logits + softmax + top8 (merge-butterfly) + dense write
__global__ __launch_bounds__(256, 2) void k_router(const float* __restrict__ P,
                                                   const float* __restrict__ embT,
                                                   float* __restrict__ out) {
    __shared__ float hsh[32][DSPACE];   // 8 KB
    const int head = blockIdx.y;
    const int t0   = blockIdx.x * 32;
    const int tid  = threadIdx.x;
    const int wid  = tid >> 6;
    const int lane = tid & 63;
    const int so = (head == 2) ? 512 : (head == 3 || head == 4) ? 1024
                 : (head == 5) ? 1536 : 0;

    // stage h tile: 32 tokens x 64 dims
    for (int idx = tid; idx < 512; idx += 256) {
        int t  = idx >> 4;
        int d4 = (idx & 15) << 2;
        *(float4*)&hsh[t][d4] =
            *(const float4*)&P[(size_t)(t0 + t) * PROJN + head * DSPACE + d4];
    }
    __syncthreads();

    // logits: wave handles 8 tokens; lane owns n = 8*lane + j
    float acc[8][8];
#pragma unroll
    for (int t = 0; t < 8; ++t)
#pragma unroll
        for (int j = 0; j < 8; ++j) acc[t][j] = 0.f;

#pragma unroll 2
    for (int d = 0; d < DSPACE; ++d) {
        const float* er = &embT[d * 2048 + so + (lane << 3)];
        float e[8];
        *(float4*)&e[0] = *(const float4*)&er[0];
        *(float4*)&e[4] = *(const float4*)&er[4];
#pragma unroll
        for (int t = 0; t < 8; ++t) {
            float hv = hsh[(wid << 3) + t][d];   // LDS broadcast
#pragma unroll
            for (int j = 0; j < 8; ++j) acc[t][j] = fmaf(hv, e[j], acc[t][j]);
        }
    }

    const size_t obase = ((size_t)head * NTOK + t0 + (wid << 3)) * NPOOL;

#pragma unroll
    for (int t = 0; t < 8; ++t) {
        float l[8], s[8];
#pragma unroll
        for (int j = 0; j < 8; ++j) { l[j] = acc[t][j]; s[j] = l[j]; }

        // ---- per-lane descending sort of 8 values (Batcher odd-even, 19 CE)
        CE(s,0,1) CE(s,2,3) CE(s,4,5) CE(s,6,7)
        CE(s,0,2) CE(s,1,3) CE(s,4,6) CE(s,5,7)
        CE(s,1,2) CE(s,5,6)
        CE(s,0,4) CE(s,1,5) CE(s,2,6) CE(s,3,7)
        CE(s,2,4) CE(s,3,5)
        CE(s,1,2) CE(s,3,4) CE(s,5,6)

        // ---- butterfly merge: after 6 steps every lane holds global top-8 desc
#pragma unroll
        for (int off = 1; off < 64; off <<= 1) {
            float q[8];
#pragma unroll
            for (int i = 0; i < 8; ++i) q[i] = __shfl_xor(s[i], off, 64);
            float c[8];
            c[0] = fmaxf(s[0], q[7]); c[1] = fmaxf(s[1], q[6]);
            c[2] = fmaxf(s[2], q[5]); c[3] = fmaxf(s[3], q[4]);
            c[4] = fmaxf(s[4], q[3]); c[5] = fmaxf(s[5], q[2]);
            c[6] = fmaxf(s[6], q[1]); c[7] = fmaxf(s[7], q[0]);
            CE(c,0,4) CE(c,1,5) CE(c,2,6) CE(c,3,7)
            CE(c,0,2) CE(c,1,3) CE(c,4,6) CE(c,5,7)
            CE(c,0,1) CE(c,2,3) CE(c,4,5) CE(c,6,7)
#pragma unroll
            for (int i = 0; i < 8; ++i) s[i] = c[i];
        }

        const float T = s[7];    // 8th largest (selection threshold)
        const float m = s[0];    // row max

        float e[8]; float zp = 0.f;
#pragma unroll
        for (int j = 0; j < 8; ++j) { e[j] = __expf(l[j] - m); zp += e[j]; }
#pragma unroll
        for (int off = 32; off >= 1; off >>= 1) zp += __shfl_xor(zp, off, 64);

        // selection: all l>T, plus (8 - #gt) of l==T by ascending global index
        unsigned gtm = 0, eqm = 0; int cgt = 0, ceq = 0;
#pragma unroll
        for (int j = 0; j < 8; ++j) {
            if (l[j] > T)       { gtm |= 1u << j; ++cgt; }
            else if (l[j] == T) { eqm |= 1u << j; ++ceq; }
        }
        int own = (ceq << 8) | cgt;
        int inc = own;
#pragma unroll
        for (int off = 1; off < 64; off <<= 1) {
            int v = __shfl_up(inc, off, 64);
            if (lane >= off) inc += v;
        }
        int tot  = __shfl(inc, 63, 64);
        int need = 8 - (tot & 0xff);
        int eqpre = (inc - own) >> 8;
        unsigned sel = gtm;
#pragma unroll
        for (int j = 0; j < 8; ++j) {
            if ((eqm >> j) & 1u) { if (eqpre < need) sel |= 1u << j; ++eqpre; }
        }

        float s8 = 0.f;
#pragma unroll
        for (int i = 0; i < 8; ++i) s8 += __expf(s[i] - m);
        float invd = 1.0f / (s8 + EPSF * zp);

        float o[8];
#pragma unroll
        for (int j = 0; j < 8; ++j)
            o[j] = ((sel >> j) & 1u) ? e[j] * invd : 0.0f;
        float4* dst = (float4*)&out[obase + (size_t)t * NPOOL + (lane << 3)];
        dst[0] = *(float4*)&o[0];
        dst[1] = *(float4*)&o[4];
    }
}

extern "C" void kernel_launch(void* const* d_in, const int* in_sizes, int n_in,
                              void* d_out, int out_size, void* d_ws, size_t ws_size,
                              hipStream_t stream) {
    const float* x   = (const float*)d_in[0];
    const float* W   = (const float*)d_in[1];
    const float* b   = (const float*)d_in[2];
    const float* emb = (const float*)d_in[3];
    float* out  = (float*)d_out;
    float* embT = (float*)d_ws;               // 64*2048 floats = 512 KB
    float* proj = embT + 64 * 2048;           // 8192*384 floats = 12.6 MB

    k_norm_emb<<<dim3(512), dim3(256), 0, stream>>>(emb, embT);
    dim3 g2(NTOK / BM, PROJN / BN);
    k_proj<<<g2, dim3(256), 0, stream>>>(x, W, b, proj);
    dim3 g3(NTOK / 32, NHEADS);
    k_router<<<g3, dim3(256), 0, stream>>>(proj, embT, out);
}